// Round 12
// baseline (428.171 us; speedup 1.0000x reference)
//
#include <hip/hip_runtime.h>
#include <hip/hip_bf16.h>
#include <stdint.h>

// ---------- types ----------
typedef __bf16 bf16x8 __attribute__((ext_vector_type(8)));
typedef float  f32x4  __attribute__((ext_vector_type(4)));
typedef unsigned short u16x8 __attribute__((ext_vector_type(8)));
typedef unsigned short u16x4 __attribute__((ext_vector_type(4)));
typedef _Float16 f16x4 __attribute__((ext_vector_type(4)));

#define HS    1024     // hidden size
#define FOURH 4096
#define SEQ   512
#define BATCH 64

#define BAR()  asm volatile("s_barrier" ::: "memory")
#define VMW(n) asm volatile("s_waitcnt vmcnt(" #n ")" ::: "memory")

// manual round-to-nearest-even f32 -> bf16 bits
__device__ __forceinline__ unsigned short f2bf(float f) {
    unsigned u = __builtin_bit_cast(unsigned, f);
    u = (u + 0x7FFFu + ((u >> 16) & 1u)) >> 16;
    return (unsigned short)u;
}

__device__ __forceinline__ void gload_lds16(const void* g, void* l) {
    __builtin_amdgcn_global_load_lds(
        (const __attribute__((address_space(1))) void*)g,
        (__attribute__((address_space(3))) void*)l, 16, 0, 0);
}

__device__ __forceinline__ float fsigmoid(float v) {
    return __builtin_amdgcn_rcpf(1.f + __expf(-v));
}
__device__ __forceinline__ float ftanh(float v) {
    return 1.f - 2.f * __builtin_amdgcn_rcpf(1.f + __expf(2.f * v));
}

// ---------- kernel 1: x (f32) -> Xb (bf16) ----------
__global__ __launch_bounds__(256) void convert_x(const float* __restrict__ x,
                                                 unsigned short* __restrict__ xb,
                                                 long n8) {
    long i = (long)blockIdx.x * blockDim.x + threadIdx.x;
    long stride = (long)gridDim.x * blockDim.x;
    for (; i < n8; i += stride) {
        const float4* p = (const float4*)(x + i * 8);
        float4 a = p[0], b = p[1];
        u16x8 o;
        o[0] = f2bf(a.x); o[1] = f2bf(a.y); o[2] = f2bf(a.z); o[3] = f2bf(a.w);
        o[4] = f2bf(b.x); o[5] = f2bf(b.y); o[6] = f2bf(b.z); o[7] = f2bf(b.w);
        *(u16x8*)(xb + i * 8) = o;
    }
}

// ---------- kernel 2: U [1024][4096] f32 -> Ut [4096][1024] bf16 ----------
__global__ __launch_bounds__(256) void transpose_u(const float* __restrict__ U,
                                                   unsigned short* __restrict__ Ut) {
    __shared__ float tile[32][33];
    int bx = blockIdx.x;            // 4096 blocks
    int tn = bx >> 5;               // n tile
    int tk = bx & 31;               // k tile
    int c = threadIdx.x & 31;
    int r = threadIdx.x >> 5;
#pragma unroll
    for (int i = 0; i < 4; ++i) {
        int k = tk * 32 + r + i * 8;
        tile[r + i * 8][c] = U[(size_t)k * FOURH + tn * 32 + c];
    }
    __syncthreads();
#pragma unroll
    for (int i = 0; i < 4; ++i) {
        int nl = r + i * 8;
        Ut[(size_t)(tn * 32 + nl) * HS + tk * 32 + c] = f2bf(tile[c][nl]);
    }
}

// ---------- kernel 3: 256x128, BK=32, ring-3, 2 blocks/CU ---------------------
// 8 waves (4M x 2N), per-wave 64x64 (acc=64 regs). LDS = 3 bufs x 24KB = 72KB
// -> 2 blocks/CU, 16 waves/CU (launch_bounds(512,4) caps 128 unified regs).
// One sync/tile: stage t+2 during t; VMW(3)+BAR at boundary retires exactly
// t+1's 3 loads (queue 3<->6, never drains until tail). Cross-block overlap
// fills barrier stalls. Subtile layout/swizzle byte-identical to r8 (0-confl).
__global__ __launch_bounds__(512, 4) void gemm_gates8(
    const unsigned short* __restrict__ Xb,   // [B*S][1024] bf16
    const unsigned short* __restrict__ Ut,   // [4096][1024] bf16
    const float* __restrict__ bias,          // [4096]
    _Float16* __restrict__ gates,            // packed [BATCH*chunk/4][4096][4]
    int lg2chunk, int s0) {
    __shared__ unsigned short LDSU[36864];   // 72KB: 3 bufs x (A 16KB | B 8KB)

    // T1: XCD-aware block swizzle (nwg multiple of 8)
    int nwg = gridDim.x;
    int bid = blockIdx.x;
    int wg = (bid & 7) * (nwg >> 3) + (bid >> 3);
    int mt = wg >> 5;            // 32 n-tiles (4096/128)
    int nt = wg & 31;

    int tid = threadIdx.x;
    int w = tid >> 6, l = tid & 63;
    int wr = w >> 1, wc = w & 1;       // wave grid 4 (M) x 2 (N)
    int lr = l & 15, lg = l >> 4;

    const int m0 = mt * 256, n0 = nt * 128;
    const int cmask = (1 << lg2chunk) - 1;

    // ds_read offset within a 16x32 subtile (ushort units), st_16x32 swizzle
    const int rdo = lr * 32 + ((lg * 8) ^ ((lr & 8) << 1));

    // staging lane geometry: lane covers row l>>2 of its subtile, k-octet (l&3)
    const int srow = l >> 2;
    const int skin = ((l & 3) * 8) ^ (((l >> 5) & 1) << 4);

    // sources: wave w stages A subtiles {2w, 2w+1} (16 rows each) + B subtile w
    const unsigned short* pA0;
    const unsigned short* pA1;
    const unsigned short* pB;
    {
        int r1 = m0 + (2 * w) * 16 + srow;
        int b1 = r1 >> lg2chunk, q1 = r1 & cmask;
        pA0 = Xb + (size_t)(b1 * SEQ + s0 + q1) * HS + skin;
        int r2 = m0 + (2 * w + 1) * 16 + srow;
        int b2 = r2 >> lg2chunk, q2 = r2 & cmask;
        pA1 = Xb + (size_t)(b2 * SEQ + s0 + q2) * HS + skin;
        pB  = Ut + (size_t)(n0 + w * 16 + srow) * HS + skin;
    }

    f32x4 acc[4][4];
#pragma unroll
    for (int mi = 0; mi < 4; ++mi)
#pragma unroll
        for (int ni = 0; ni < 4; ++ni) acc[mi][ni] = 0.f;

#define STG(T, dst) { \
    gload_lds16(pA0 + (T) * 32, (dst) + (2 * w) * 512); \
    gload_lds16(pA1 + (T) * 32, (dst) + (2 * w + 1) * 512); \
    gload_lds16(pB  + (T) * 32, (dst) + 8192 + w * 512); }

    unsigned short* b0 = &LDSU[0];
    unsigned short* b1 = &LDSU[12288];
    unsigned short* b2 = &LDSU[24576];

    // prologue: stage tiles 0,1; confirm tile 0 (retire its 3, leave t1's 3)
    STG(0, b0); STG(1, b1);
    VMW(3); BAR();

    bf16x8 av[4], bv[4];
    for (int t = 0; t < 32; ++t) {
        // fragment reads of tile t (buf b0)
#pragma unroll
        for (int mi = 0; mi < 4; ++mi)
            av[mi] = *(const bf16x8*)(b0 + (wr * 4 + mi) * 512 + rdo);
#pragma unroll
        for (int ni = 0; ni < 4; ++ni)
            bv[ni] = *(const bf16x8*)(b0 + 8192 + (wc * 4 + ni) * 512 + rdo);
        if (t < 30) STG(t + 2, b2);
        __builtin_amdgcn_s_setprio(1);
#pragma unroll
        for (int mi = 0; mi < 4; ++mi)
#pragma unroll
            for (int ni = 0; ni < 4; ++ni)
                acc[mi][ni] = __builtin_amdgcn_mfma_f32_16x16x32_bf16(
                    av[mi], bv[ni], acc[mi][ni], 0, 0, 0);
        __builtin_amdgcn_s_setprio(0);
        if (t < 30)      { VMW(3); }     // retire t+1's 3 loads, keep t+2's
        else if (t == 30){ VMW(0); }     // tail: confirm tile 31
        if (t < 31) BAR();
        unsigned short* tmp = b0; b0 = b1; b1 = b2; b2 = tmp;
    }
#undef STG

    // ---- epilogue: bias + act, direct packed f16x4 stores ----
    // C/D map: col = lane&15, row = (lane>>4)*4 + r
#pragma unroll
    for (int ni = 0; ni < 4; ++ni) {
        int gcol = n0 + wc * 64 + ni * 16 + lr;
        bool is_g = ((gcol >> 10) == 2);
        float bv2 = bias[gcol];
#pragma unroll
        for (int mi = 0; mi < 4; ++mi) {
            int rg = ((m0 + wr * 64 + mi * 16) >> 2) + lg;   // row-group
            u16x4 pk;
#pragma unroll
            for (int r = 0; r < 4; ++r) {
                float v = acc[mi][ni][r] + bv2;
                float e = is_g ? ftanh(v) : fsigmoid(v);
                pk[r] = __builtin_bit_cast(unsigned short, (_Float16)e);
            }
            *(u16x4*)(gates + ((size_t)rg * FOURH + gcol) * 4) = pk;
        }
    }
}

// ---------- kernel 4: recurrence on packed gates, one thread per (b,h) -------
__global__ __launch_bounds__(256) void lstm_recur(
    const _Float16* __restrict__ gates,  // packed [rows/4][4096][4] activated
    float* __restrict__ out,             // d_out base (f32)
    float* __restrict__ cstate,          // [65536]
    int chunk, int s0) {
    int t = blockIdx.x * 256 + threadIdx.x;  // 0..65535
    int b = t >> 10, h = t & 1023;
    float c = (s0 == 0) ? 0.f : cstate[t];
    const _Float16* gp = gates + ((size_t)((b * chunk) >> 2) * FOURH + h) * 4;
    float* op = out + (size_t)(b * SEQ + s0) * HS + h;
    float hv = 0.f;
    const int ng = chunk >> 2;               // row-groups of 4 steps
    for (int g4 = 0; g4 < ng; g4 += 2) {
        f16x4 iv[2], fv[2], gv[2], ov[2];
#pragma unroll
        for (int u = 0; u < 2; ++u) {
            const _Float16* q = gp + (size_t)(g4 + u) * (FOURH * 4);
            iv[u] = *(const f16x4*)(q);
            fv[u] = *(const f16x4*)(q + 4096);
            gv[u] = *(const f16x4*)(q + 8192);
            ov[u] = *(const f16x4*)(q + 12288);
        }
#pragma unroll
        for (int u = 0; u < 2; ++u) {
#pragma unroll
            for (int r = 0; r < 4; ++r) {
                c = (float)fv[u][r] * c + (float)iv[u][r] * (float)gv[u][r];
                float th = ftanh(c);
                hv = (float)ov[u][r] * th;
                op[(size_t)((g4 + u) * 4 + r) * HS] = hv;
            }
        }
    }
    cstate[t] = c;
    if (s0 + chunk == SEQ) {
        out[(size_t)BATCH * SEQ * HS + t] = hv;                      // h_T
        out[(size_t)BATCH * SEQ * HS + BATCH * HS + t] = c;          // c_T
    }
}

// ---------- launcher ----------
extern "C" void kernel_launch(void* const* d_in, const int* in_sizes, int n_in,
                              void* d_out, int out_size, void* d_ws, size_t ws_size,
                              hipStream_t stream) {
    const float* x    = (const float*)d_in[0];
    const float* U    = (const float*)d_in[1];
    const float* bias = (const float*)d_in[2];
    float* out = (float*)d_out;
    char*  ws  = (char*)d_ws;

    // ws layout
    unsigned short* Xb = (unsigned short*)ws;                   // 64MB  bf16 x
    unsigned short* Ut = (unsigned short*)(ws + 67108864);      // 8MB   bf16 U^T
    float* cstate      = (float*)(ws + 75497472);               // 256KB
    _Float16* gates    = (_Float16*)(ws + 75759616);            // chunk*0.5MB
    const size_t fixed = 75759616;

    int chunk = 512;
    while (chunk > 4 && fixed + (size_t)BATCH * chunk * FOURH * 2 > ws_size)
        chunk >>= 1;
    int lg2 = 31 - __builtin_clz(chunk);

    convert_x<<<2048, 256, 0, stream>>>(x, Xb, (long)BATCH * SEQ * HS / 8);
    transpose_u<<<4096, 256, 0, stream>>>(U, Ut);

    for (int s0 = 0; s0 < SEQ; s0 += chunk) {
        int mtiles = (BATCH * chunk) / 256;
        gemm_gates8<<<mtiles * 32, 512, 0, stream>>>(Xb, Ut, bias, gates, lg2, s0);
        lstm_recur<<<256, 256, 0, stream>>>(gates, out, cstate, chunk, s0);
    }
}

// Round 13
// 400.515 us; speedup vs baseline: 1.0691x; 1.0691x over previous
//
#include <hip/hip_runtime.h>
#include <hip/hip_bf16.h>
#include <stdint.h>

// ---------- types ----------
typedef __bf16 bf16x8 __attribute__((ext_vector_type(8)));
typedef float  f32x4  __attribute__((ext_vector_type(4)));
typedef unsigned short u16x8 __attribute__((ext_vector_type(8)));
typedef unsigned short u16x4 __attribute__((ext_vector_type(4)));
typedef _Float16 f16x4 __attribute__((ext_vector_type(4)));

#define HS    1024     // hidden size
#define FOURH 4096
#define SEQ   512
#define BATCH 64

#define BAR()  asm volatile("s_barrier" ::: "memory")
#define VMW(n) asm volatile("s_waitcnt vmcnt(" #n ")" ::: "memory")

// manual round-to-nearest-even f32 -> bf16 bits
__device__ __forceinline__ unsigned short f2bf(float f) {
    unsigned u = __builtin_bit_cast(unsigned, f);
    u = (u + 0x7FFFu + ((u >> 16) & 1u)) >> 16;
    return (unsigned short)u;
}

__device__ __forceinline__ void gload_lds16(const void* g, void* l) {
    __builtin_amdgcn_global_load_lds(
        (const __attribute__((address_space(1))) void*)g,
        (__attribute__((address_space(3))) void*)l, 16, 0, 0);
}

__device__ __forceinline__ float fsigmoid(float v) {
    return __builtin_amdgcn_rcpf(1.f + __expf(-v));
}
__device__ __forceinline__ float ftanh(float v) {
    return 1.f - 2.f * __builtin_amdgcn_rcpf(1.f + __expf(2.f * v));
}

// ---------- kernel 1: x (f32) -> Xb (bf16) ----------
__global__ __launch_bounds__(256) void convert_x(const float* __restrict__ x,
                                                 unsigned short* __restrict__ xb,
                                                 long n8) {
    long i = (long)blockIdx.x * blockDim.x + threadIdx.x;
    long stride = (long)gridDim.x * blockDim.x;
    for (; i < n8; i += stride) {
        const float4* p = (const float4*)(x + i * 8);
        float4 a = p[0], b = p[1];
        u16x8 o;
        o[0] = f2bf(a.x); o[1] = f2bf(a.y); o[2] = f2bf(a.z); o[3] = f2bf(a.w);
        o[4] = f2bf(b.x); o[5] = f2bf(b.y); o[6] = f2bf(b.z); o[7] = f2bf(b.w);
        *(u16x8*)(xb + i * 8) = o;
    }
}

// ---------- kernel 2: U [1024][4096] f32 -> Ut [4096][1024] bf16 ----------
__global__ __launch_bounds__(256) void transpose_u(const float* __restrict__ U,
                                                   unsigned short* __restrict__ Ut) {
    __shared__ float tile[32][33];
    int bx = blockIdx.x;            // 4096 blocks
    int tn = bx >> 5;               // n tile
    int tk = bx & 31;               // k tile
    int c = threadIdx.x & 31;
    int r = threadIdx.x >> 5;
#pragma unroll
    for (int i = 0; i < 4; ++i) {
        int k = tk * 32 + r + i * 8;
        tile[r + i * 8][c] = U[(size_t)k * FOURH + tn * 32 + c];
    }
    __syncthreads();
#pragma unroll
    for (int i = 0; i < 4; ++i) {
        int nl = r + i * 8;
        Ut[(size_t)(tn * 32 + nl) * HS + tk * 32 + c] = f2bf(tile[c][nl]);
    }
}

// ---------- kernel 3: 256x256, BK=64 GEMM (r8/r9 best: 282us, 43%, 0 confl) --
__global__ __launch_bounds__(512, 1) void gemm_gates8(
    const unsigned short* __restrict__ Xb,   // [B*S][1024] bf16
    const unsigned short* __restrict__ Ut,   // [4096][1024] bf16
    const float* __restrict__ bias,          // [4096]
    _Float16* __restrict__ gates,            // packed [BATCH*chunk/4][4096][4]
    int lg2chunk, int s0) {
    __shared__ unsigned short LDSU[65536];   // 128KB: buf(t&1)*32768; A@0, B@+16384

    int nwg = gridDim.x;
    int bid = blockIdx.x;
    int wg = (bid & 7) * (nwg >> 3) + (bid >> 3);
    int mt = wg >> 4;            // 16 n-tiles (4096/256)
    int nt = wg & 15;

    int tid = threadIdx.x;
    int w = tid >> 6, l = tid & 63;
    int wr = w >> 2, wc = w & 3;       // wave grid 2 (M) x 4 (N)
    int lr = l & 15, lg = l >> 4;

    const int m0 = mt * 256, n0 = nt * 256;
    const int cmask = (1 << lg2chunk) - 1;

    const int rdo = lr * 32 + ((lg * 8) ^ ((lr & 8) << 1));
    const int srow = l >> 2;
    const int skin = ((l & 3) * 8) ^ (((l >> 5) & 1) << 4);

    const unsigned short* pAq[4];
    const unsigned short* pBq[4];
#pragma unroll
    for (int q = 0; q < 4; ++q) {
        int rowg = q * 64 + (w >> 1) * 16 + srow;
        int mrow = m0 + rowg;
        int b = mrow >> lg2chunk, sl2 = mrow & cmask;
        pAq[q] = Xb + (size_t)(b * SEQ + s0 + sl2) * HS + (w & 1) * 32 + skin;
        pBq[q] = Ut + (size_t)(n0 + rowg) * HS + (w & 1) * 32 + skin;
    }
    const int dsub = (w >> 1) * 2 + (w & 1);

    f32x4 acc[8][4];
#pragma unroll
    for (int mi = 0; mi < 8; ++mi)
#pragma unroll
        for (int ni = 0; ni < 4; ++ni) acc[mi][ni] = 0.f;

#define SA(T, Q) gload_lds16(pAq[Q] + (T) * 64, \
        &LDSU[(((T) & 1) << 15) + ((Q) * 8 + dsub) * 512])
#define SB(T, Q) gload_lds16(pBq[Q] + (T) * 64, \
        &LDSU[(((T) & 1) << 15) + 16384 + ((Q) * 8 + dsub) * 512])

    bf16x8 aq[2][4], bn0[2][2], bn1[2][2];

#define RDA(MH) \
    _Pragma("unroll") for (int ks = 0; ks < 2; ++ks) \
    _Pragma("unroll") for (int mi = 0; mi < 4; ++mi) \
        aq[ks][mi] = *(const bf16x8*)(buf + ((wr * 8 + (MH) * 4 + mi) * 2 + ks) * 512 + rdo)
#define RDB(NH, BN) \
    _Pragma("unroll") for (int ks = 0; ks < 2; ++ks) \
    _Pragma("unroll") for (int ni = 0; ni < 2; ++ni) \
        BN[ks][ni] = *(const bf16x8*)(buf + 16384 + ((wc * 4 + (NH) * 2 + ni) * 2 + ks) * 512 + rdo)
#define MMQ(MH, NH, BN) \
    __builtin_amdgcn_s_setprio(1); \
    _Pragma("unroll") for (int ks = 0; ks < 2; ++ks) \
    _Pragma("unroll") for (int mi = 0; mi < 4; ++mi) \
    _Pragma("unroll") for (int ni = 0; ni < 2; ++ni) \
        acc[(MH) * 4 + mi][(NH) * 2 + ni] = __builtin_amdgcn_mfma_f32_16x16x32_bf16( \
            aq[ks][mi], BN[ks][ni], acc[(MH) * 4 + mi][(NH) * 2 + ni], 0, 0, 0); \
    __builtin_amdgcn_s_setprio(0)

    SA(0, 0); SA(0, 2); SB(0, 0); SB(0, 1); SB(0, 2); SB(0, 3); SA(0, 1); SA(0, 3);
    VMW(2); BAR();

    for (int t = 0; t < 16; ++t) {
        const unsigned short* buf = &LDSU[(t & 1) << 15];
        // ---- region 1: Q(0,0) + Q(0,1); stage ALL R1-needs of t+1 ----
        RDA(0);
        RDB(0, bn0);
        if (t < 15) { SA(t + 1, 0); SA(t + 1, 2); }
        MMQ(0, 0, bn0);
        RDB(1, bn1);
        if (t < 15) { SB(t + 1, 0); SB(t + 1, 1); SB(t + 1, 2); SB(t + 1, 3); }
        MMQ(0, 1, bn1);
        if (t < 15) { VMW(6); } else { VMW(0); }
        BAR();
        // ---- region 2: Q(1,1) + Q(1,0); stage A1,A3 of t+1 ----
        RDA(1);
        if (t < 15) { SA(t + 1, 1); SA(t + 1, 3); }
        MMQ(1, 1, bn1);
        MMQ(1, 0, bn0);
        if (t < 15) { VMW(2); }
        BAR();
    }

    // ---- epilogue: bias + act, direct packed f16x4 stores ----
#pragma unroll
    for (int ni = 0; ni < 4; ++ni) {
        int gcol = n0 + wc * 64 + ni * 16 + lr;
        bool is_g = ((gcol >> 10) == 2);
        float bv = bias[gcol];
#pragma unroll
        for (int mi = 0; mi < 8; ++mi) {
            int rg = ((m0 + wr * 128 + mi * 16) >> 2) + lg;   // row-group
            u16x4 pk;
#pragma unroll
            for (int r = 0; r < 4; ++r) {
                float v = acc[mi][ni][r] + bv;
                float e = is_g ? ftanh(v) : fsigmoid(v);
                pk[r] = __builtin_bit_cast(unsigned short, (_Float16)e);
            }
            *(u16x4*)(gates + ((size_t)rg * FOURH + gcol) * 4) = pk;
        }
    }
#undef SA
#undef SB
#undef RDA
#undef RDB
#undef MMQ
}

// ---------- kernel 4: recurrence, block-cooperative LDS-staged ---------------
// 256 blocks x 256 thr. Block = (b, h-quarter): 256 chains. Per 16-step burst
// the block stages 32KB of gates (16 stripes x 2KB) via global_load_lds into
// a 2x32KB LDS double buffer (8 coalesced 16B loads/thread, 32KB in flight/CU
// -> BW-bound). stage(m+1); VMW(8) retires stage(m); BAR; compute; BAR (WAR).
__global__ __launch_bounds__(256) void lstm_recur_lds(
    const _Float16* __restrict__ gates,  // packed [rows/4][4096][4] activated
    float* __restrict__ out,             // d_out base (f32)
    float* __restrict__ cstate,          // [65536]
    int chunk, int s0) {
    __shared__ unsigned char LB[2][32768];

    int tid = threadIdx.x;
    int b = blockIdx.x >> 2;
    int h0 = (blockIdx.x & 3) * 256;
    int h = h0 + tid;
    int tg = b * HS + h;

    float c = (s0 == 0) ? 0.f : cstate[tg];
    float hv = 0.f;
    const size_t rgbase = (size_t)(b * chunk) >> 2;
    const char* gbase = (const char*)gates;
    float* op = out + (size_t)(b * SEQ + s0) * HS + h;

    const int M = chunk >> 4;                 // bursts of 16 steps
    const int wbase = (tid & 0xC0) * 16;      // wave-uniform dst component

    auto STAGE = [&](int m) {
        unsigned char* dst0 = &LB[m & 1][0];
        size_t rg0 = rgbase + (size_t)m * 4;
#pragma unroll
        for (int j = 0; j < 8; ++j) {
            int q = j * 256 + tid;            // 16B unit id 0..2047
            int stripe = q >> 7;              // rg*4 + gate
            int u = q & 127;
            const char* src = gbase +
                ((rg0 + (stripe >> 2)) * FOURH + (stripe & 3) * 1024 + h0 + u * 2) * 8;
            gload_lds16(src, dst0 + j * 4096 + wbase);
        }
    };

    STAGE(0);
    for (int m = 0; m < M; ++m) {
        if (m + 1 < M) { STAGE(m + 1); VMW(8); }
        else           { VMW(0); }
        BAR();
        const unsigned char* sb = &LB[m & 1][0];
#pragma unroll
        for (int rg = 0; rg < 4; ++rg) {
            f16x4 iv = *(const f16x4*)(sb + ((rg * 4 + 0) * 2048) + tid * 8);
            f16x4 fv = *(const f16x4*)(sb + ((rg * 4 + 1) * 2048) + tid * 8);
            f16x4 gv = *(const f16x4*)(sb + ((rg * 4 + 2) * 2048) + tid * 8);
            f16x4 ov = *(const f16x4*)(sb + ((rg * 4 + 3) * 2048) + tid * 8);
#pragma unroll
            for (int r = 0; r < 4; ++r) {
                c = (float)fv[r] * c + (float)iv[r] * (float)gv[r];
                float th = ftanh(c);
                hv = (float)ov[r] * th;
                op[(size_t)(m * 16 + rg * 4 + r) * HS] = hv;
            }
        }
        BAR();
    }
    cstate[tg] = c;
    if (s0 + chunk == SEQ) {
        out[(size_t)BATCH * SEQ * HS + tg] = hv;                     // h_T
        out[(size_t)BATCH * SEQ * HS + BATCH * HS + tg] = c;         // c_T
    }
}

// ---------- kernel 4b: fallback scalar recurrence (chunk not mult of 16) -----
__global__ __launch_bounds__(256) void lstm_recur(
    const _Float16* __restrict__ gates,
    float* __restrict__ out, float* __restrict__ cstate,
    int chunk, int s0) {
    int t = blockIdx.x * 256 + threadIdx.x;
    int b = t >> 10, h = t & 1023;
    float c = (s0 == 0) ? 0.f : cstate[t];
    const _Float16* gp = gates + ((size_t)((b * chunk) >> 2) * FOURH + h) * 4;
    float* op = out + (size_t)(b * SEQ + s0) * HS + h;
    float hv = 0.f;
    const int ng = chunk >> 2;
    for (int g4 = 0; g4 < ng; ++g4) {
        const _Float16* q = gp + (size_t)g4 * (FOURH * 4);
        f16x4 iv = *(const f16x4*)(q);
        f16x4 fv = *(const f16x4*)(q + 4096);
        f16x4 gv = *(const f16x4*)(q + 8192);
        f16x4 ov = *(const f16x4*)(q + 12288);
#pragma unroll
        for (int r = 0; r < 4; ++r) {
            c = (float)fv[r] * c + (float)iv[r] * (float)gv[r];
            float th = ftanh(c);
            hv = (float)ov[r] * th;
            op[(size_t)(g4 * 4 + r) * HS] = hv;
        }
    }
    cstate[t] = c;
    if (s0 + chunk == SEQ) {
        out[(size_t)BATCH * SEQ * HS + t] = hv;
        out[(size_t)BATCH * SEQ * HS + BATCH * HS + t] = c;
    }
}

// ---------- launcher ----------
extern "C" void kernel_launch(void* const* d_in, const int* in_sizes, int n_in,
                              void* d_out, int out_size, void* d_ws, size_t ws_size,
                              hipStream_t stream) {
    const float* x    = (const float*)d_in[0];
    const float* U    = (const float*)d_in[1];
    const float* bias = (const float*)d_in[2];
    float* out = (float*)d_out;
    char*  ws  = (char*)d_ws;

    // ws layout
    unsigned short* Xb = (unsigned short*)ws;                   // 64MB  bf16 x
    unsigned short* Ut = (unsigned short*)(ws + 67108864);      // 8MB   bf16 U^T
    float* cstate      = (float*)(ws + 75497472);               // 256KB
    _Float16* gates    = (_Float16*)(ws + 75759616);            // chunk*0.5MB
    const size_t fixed = 75759616;

    int chunk = 512;
    while (chunk > 4 && fixed + (size_t)BATCH * chunk * FOURH * 2 > ws_size)
        chunk >>= 1;
    int lg2 = 31 - __builtin_clz(chunk);

    convert_x<<<2048, 256, 0, stream>>>(x, Xb, (long)BATCH * SEQ * HS / 8);
    transpose_u<<<4096, 256, 0, stream>>>(U, Ut);

    for (int s0 = 0; s0 < SEQ; s0 += chunk) {
        int mtiles = (BATCH * chunk) / 256;
        gemm_gates8<<<mtiles * 16, 512, 0, stream>>>(Xb, Ut, bias, gates, lg2, s0);
        if ((chunk & 15) == 0)
            lstm_recur_lds<<<256, 256, 0, stream>>>(gates, out, cstate, chunk, s0);
        else
            lstm_recur<<<256, 256, 0, stream>>>(gates, out, cstate, chunk, s0);
    }
}

// Round 14
// 376.457 us; speedup vs baseline: 1.1374x; 1.0639x over previous
//
#include <hip/hip_runtime.h>
#include <hip/hip_bf16.h>
#include <stdint.h>

// ---------- types ----------
typedef __bf16 bf16x8 __attribute__((ext_vector_type(8)));
typedef float  f32x4  __attribute__((ext_vector_type(4)));
typedef unsigned short u16x8 __attribute__((ext_vector_type(8)));
typedef unsigned short u16x4 __attribute__((ext_vector_type(4)));
typedef _Float16 f16x4 __attribute__((ext_vector_type(4)));

#define HS    1024     // hidden size
#define FOURH 4096
#define SEQ   512
#define BATCH 64

#define BAR()  asm volatile("s_barrier" ::: "memory")
#define VMW(n) asm volatile("s_waitcnt vmcnt(" #n ")" ::: "memory")

// manual round-to-nearest-even f32 -> bf16 bits
__device__ __forceinline__ unsigned short f2bf(float f) {
    unsigned u = __builtin_bit_cast(unsigned, f);
    u = (u + 0x7FFFu + ((u >> 16) & 1u)) >> 16;
    return (unsigned short)u;
}

__device__ __forceinline__ void gload_lds16(const void* g, void* l) {
    __builtin_amdgcn_global_load_lds(
        (const __attribute__((address_space(1))) void*)g,
        (__attribute__((address_space(3))) void*)l, 16, 0, 0);
}

__device__ __forceinline__ float fsigmoid(float v) {
    return __builtin_amdgcn_rcpf(1.f + __expf(-v));
}
__device__ __forceinline__ float ftanh(float v) {
    return 1.f - 2.f * __builtin_amdgcn_rcpf(1.f + __expf(2.f * v));
}

// ---------- kernel 1: x (f32) -> Xb (bf16) ----------
__global__ __launch_bounds__(256) void convert_x(const float* __restrict__ x,
                                                 unsigned short* __restrict__ xb,
                                                 long n8) {
    long i = (long)blockIdx.x * blockDim.x + threadIdx.x;
    long stride = (long)gridDim.x * blockDim.x;
    for (; i < n8; i += stride) {
        const float4* p = (const float4*)(x + i * 8);
        float4 a = p[0], b = p[1];
        u16x8 o;
        o[0] = f2bf(a.x); o[1] = f2bf(a.y); o[2] = f2bf(a.z); o[3] = f2bf(a.w);
        o[4] = f2bf(b.x); o[5] = f2bf(b.y); o[6] = f2bf(b.z); o[7] = f2bf(b.w);
        *(u16x8*)(xb + i * 8) = o;
    }
}

// ---------- kernel 2: U [1024][4096] f32 -> Ut[perm(n)][k] bf16 --------------
// Column permutation interleaves gates: perm(gate*1024+h) = (h>>4)*64 +
// gate*16 + (h&15), so each 64-col slice = 16 h's x 4 gates (epilogue fusion).
__global__ __launch_bounds__(256) void transpose_u(const float* __restrict__ U,
                                                   unsigned short* __restrict__ Ut) {
    __shared__ float tile[32][33];
    int bx = blockIdx.x;            // 4096 blocks
    int tn = bx >> 5;               // n tile
    int tk = bx & 31;               // k tile
    int c = threadIdx.x & 31;
    int r = threadIdx.x >> 5;
#pragma unroll
    for (int i = 0; i < 4; ++i) {
        int k = tk * 32 + r + i * 8;
        tile[r + i * 8][c] = U[(size_t)k * FOURH + tn * 32 + c];
    }
    __syncthreads();
#pragma unroll
    for (int i = 0; i < 4; ++i) {
        int nl = r + i * 8;
        int n = tn * 32 + nl;
        int gate = n >> 10, h = n & 1023;
        int pn = ((h >> 4) << 6) | (gate << 4) | (h & 15);
        Ut[(size_t)pn * HS + tk * 32 + c] = f2bf(tile[c][nl]);
    }
}

// ---------- kernel 3: 256x256, BK=64 GEMM (r8 core) + fused p=i*g epilogue ---
// Gate-interleaved B: lane lr holds h = (n0/64+wc)*16+lr for ALL ni=gate.
// Epilogue computes p=sig(i)*tanh(g), f, o in-register; stores 3 f16 planes
// [rg][{p,f,o}][4096] (25% less gates traffic than 4-gate storage).
__global__ __launch_bounds__(512, 1) void gemm_gates8(
    const unsigned short* __restrict__ Xb,   // [B*S][1024] bf16
    const unsigned short* __restrict__ Ut,   // [4096 perm][1024] bf16
    const float* __restrict__ bias,          // [4096] original order
    _Float16* __restrict__ gates,            // packed [rows/4][3][4096]
    int lg2chunk, int s0) {
    __shared__ unsigned short LDSU[65536];   // 128KB: buf(t&1)*32768; A@0, B@+16384

    int nwg = gridDim.x;
    int bid = blockIdx.x;
    int wg = (bid & 7) * (nwg >> 3) + (bid >> 3);
    int mt = wg >> 4;            // 16 n-tiles (4096/256)
    int nt = wg & 15;

    int tid = threadIdx.x;
    int w = tid >> 6, l = tid & 63;
    int wr = w >> 2, wc = w & 3;       // wave grid 2 (M) x 4 (N)
    int lr = l & 15, lg = l >> 4;

    const int m0 = mt * 256, n0 = nt * 256;
    const int cmask = (1 << lg2chunk) - 1;

    const int rdo = lr * 32 + ((lg * 8) ^ ((lr & 8) << 1));
    const int srow = l >> 2;
    const int skin = ((l & 3) * 8) ^ (((l >> 5) & 1) << 4);

    const unsigned short* pAq[4];
    const unsigned short* pBq[4];
#pragma unroll
    for (int q = 0; q < 4; ++q) {
        int rowg = q * 64 + (w >> 1) * 16 + srow;
        int mrow = m0 + rowg;
        int b = mrow >> lg2chunk, sl2 = mrow & cmask;
        pAq[q] = Xb + (size_t)(b * SEQ + s0 + sl2) * HS + (w & 1) * 32 + skin;
        pBq[q] = Ut + (size_t)(n0 + rowg) * HS + (w & 1) * 32 + skin;
    }
    const int dsub = (w >> 1) * 2 + (w & 1);

    f32x4 acc[8][4];
#pragma unroll
    for (int mi = 0; mi < 8; ++mi)
#pragma unroll
        for (int ni = 0; ni < 4; ++ni) acc[mi][ni] = 0.f;

#define SA(T, Q) gload_lds16(pAq[Q] + (T) * 64, \
        &LDSU[(((T) & 1) << 15) + ((Q) * 8 + dsub) * 512])
#define SB(T, Q) gload_lds16(pBq[Q] + (T) * 64, \
        &LDSU[(((T) & 1) << 15) + 16384 + ((Q) * 8 + dsub) * 512])

    bf16x8 aq[2][4], bn0[2][2], bn1[2][2];

#define RDA(MH) \
    _Pragma("unroll") for (int ks = 0; ks < 2; ++ks) \
    _Pragma("unroll") for (int mi = 0; mi < 4; ++mi) \
        aq[ks][mi] = *(const bf16x8*)(buf + ((wr * 8 + (MH) * 4 + mi) * 2 + ks) * 512 + rdo)
#define RDB(NH, BN) \
    _Pragma("unroll") for (int ks = 0; ks < 2; ++ks) \
    _Pragma("unroll") for (int ni = 0; ni < 2; ++ni) \
        BN[ks][ni] = *(const bf16x8*)(buf + 16384 + ((wc * 4 + (NH) * 2 + ni) * 2 + ks) * 512 + rdo)
#define MMQ(MH, NH, BN) \
    __builtin_amdgcn_s_setprio(1); \
    _Pragma("unroll") for (int ks = 0; ks < 2; ++ks) \
    _Pragma("unroll") for (int mi = 0; mi < 4; ++mi) \
    _Pragma("unroll") for (int ni = 0; ni < 2; ++ni) \
        acc[(MH) * 4 + mi][(NH) * 2 + ni] = __builtin_amdgcn_mfma_f32_16x16x32_bf16( \
            aq[ks][mi], BN[ks][ni], acc[(MH) * 4 + mi][(NH) * 2 + ni], 0, 0, 0); \
    __builtin_amdgcn_s_setprio(0)

    SA(0, 0); SA(0, 2); SB(0, 0); SB(0, 1); SB(0, 2); SB(0, 3); SA(0, 1); SA(0, 3);
    VMW(2); BAR();

    for (int t = 0; t < 16; ++t) {
        const unsigned short* buf = &LDSU[(t & 1) << 15];
        // ---- region 1: Q(0,0) + Q(0,1); stage ALL R1-needs of t+1 ----
        RDA(0);
        RDB(0, bn0);
        if (t < 15) { SA(t + 1, 0); SA(t + 1, 2); }
        MMQ(0, 0, bn0);
        RDB(1, bn1);
        if (t < 15) { SB(t + 1, 0); SB(t + 1, 1); SB(t + 1, 2); SB(t + 1, 3); }
        MMQ(0, 1, bn1);
        if (t < 15) { VMW(6); } else { VMW(0); }
        BAR();
        // ---- region 2: Q(1,1) + Q(1,0); stage A1,A3 of t+1 ----
        RDA(1);
        if (t < 15) { SA(t + 1, 1); SA(t + 1, 3); }
        MMQ(1, 1, bn1);
        MMQ(1, 0, bn0);
        if (t < 15) { VMW(2); }
        BAR();
    }

    // ---- epilogue: fused p = sig(i)*tanh(g); store p,f,o planes ----
    // ni = gate (0:i 1:f 2:g 3:o); lane h = (n0/64 + wc)*16 + lr for all ni.
    const int hh = ((n0 >> 6) + wc) * 16 + lr;
    const float bi = bias[hh], bf = bias[1024 + hh];
    const float bg = bias[2048 + hh], bo = bias[3072 + hh];
#pragma unroll
    for (int mi = 0; mi < 8; ++mi) {
        size_t rg = (size_t)(((m0 + wr * 128 + mi * 16) >> 2) + lg);
        u16x4 pkP, pkF, pkO;
#pragma unroll
        for (int r = 0; r < 4; ++r) {
            float iv = fsigmoid(acc[mi][0][r] + bi);
            float fv = fsigmoid(acc[mi][1][r] + bf);
            float gv = ftanh(acc[mi][2][r] + bg);
            float ov = fsigmoid(acc[mi][3][r] + bo);
            float pv = iv * gv;
            pkP[r] = __builtin_bit_cast(unsigned short, (_Float16)pv);
            pkF[r] = __builtin_bit_cast(unsigned short, (_Float16)fv);
            pkO[r] = __builtin_bit_cast(unsigned short, (_Float16)ov);
        }
        _Float16* gp = gates + rg * 12288 + hh * 4;
        *(u16x4*)(gp)        = pkP;
        *(u16x4*)(gp + 4096) = pkF;
        *(u16x4*)(gp + 8192) = pkO;
    }
#undef SA
#undef SB
#undef RDA
#undef RDB
#undef MMQ
}

// ---------- kernel 4: recurrence on p,f,o planes, one thread per (b,h) -------
__global__ __launch_bounds__(256) void lstm_recur(
    const _Float16* __restrict__ gates,  // [rg][{p,f,o}][4096] f16
    float* __restrict__ out,             // d_out base (f32)
    float* __restrict__ cstate,          // [65536]
    int chunk, int s0) {
    int t = blockIdx.x * 256 + threadIdx.x;  // 0..65535
    int b = t >> 10, h = t & 1023;
    float c = (s0 == 0) ? 0.f : cstate[t];
    const _Float16* gp = gates + (size_t)((b * chunk) >> 2) * 12288 + h * 4;
    float* op = out + (size_t)(b * SEQ + s0) * HS + h;
    float hv = 0.f;
    const int ng = chunk >> 2;               // row-groups of 4 steps
    int g4 = 0;
    for (; g4 + 1 < ng; g4 += 2) {
        f16x4 pv[2], fv[2], ov[2];
#pragma unroll
        for (int u = 0; u < 2; ++u) {
            const _Float16* q = gp + (size_t)(g4 + u) * 12288;
            pv[u] = *(const f16x4*)(q);
            fv[u] = *(const f16x4*)(q + 4096);
            ov[u] = *(const f16x4*)(q + 8192);
        }
#pragma unroll
        for (int u = 0; u < 2; ++u) {
#pragma unroll
            for (int r = 0; r < 4; ++r) {
                c = (float)fv[u][r] * c + (float)pv[u][r];
                float th = ftanh(c);
                hv = (float)ov[u][r] * th;
                op[(size_t)((g4 + u) * 4 + r) * HS] = hv;
            }
        }
    }
    for (; g4 < ng; ++g4) {                  // tail (odd ng)
        const _Float16* q = gp + (size_t)g4 * 12288;
        f16x4 pv = *(const f16x4*)(q);
        f16x4 fv = *(const f16x4*)(q + 4096);
        f16x4 ov = *(const f16x4*)(q + 8192);
#pragma unroll
        for (int r = 0; r < 4; ++r) {
            c = (float)fv[r] * c + (float)pv[r];
            float th = ftanh(c);
            hv = (float)ov[r] * th;
            op[(size_t)(g4 * 4 + r) * HS] = hv;
        }
    }
    cstate[t] = c;
    if (s0 + chunk == SEQ) {
        out[(size_t)BATCH * SEQ * HS + t] = hv;                      // h_T
        out[(size_t)BATCH * SEQ * HS + BATCH * HS + t] = c;          // c_T
    }
}

// ---------- launcher ----------
extern "C" void kernel_launch(void* const* d_in, const int* in_sizes, int n_in,
                              void* d_out, int out_size, void* d_ws, size_t ws_size,
                              hipStream_t stream) {
    const float* x    = (const float*)d_in[0];
    const float* U    = (const float*)d_in[1];
    const float* bias = (const float*)d_in[2];
    float* out = (float*)d_out;
    char*  ws  = (char*)d_ws;

    // ws layout
    unsigned short* Xb = (unsigned short*)ws;                   // 64MB  bf16 x
    unsigned short* Ut = (unsigned short*)(ws + 67108864);      // 8MB   bf16 U^T
    float* cstate      = (float*)(ws + 75497472);               // 256KB
    _Float16* gates    = (_Float16*)(ws + 75759616);            // chunk*0.375MB
    const size_t fixed = 75759616;

    int chunk = 512;
    while (chunk > 4 && fixed + (size_t)BATCH * chunk * 6144 > ws_size)
        chunk >>= 1;
    int lg2 = 31 - __builtin_clz(chunk);

    convert_x<<<2048, 256, 0, stream>>>(x, Xb, (long)BATCH * SEQ * HS / 8);
    transpose_u<<<4096, 256, 0, stream>>>(U, Ut);

    for (int s0 = 0; s0 < SEQ; s0 += chunk) {
        int mtiles = (BATCH * chunk) / 256;
        gemm_gates8<<<mtiles * 16, 512, 0, stream>>>(Xb, Ut, bias, gates, lg2, s0);
        lstm_recur<<<256, 256, 0, stream>>>(gates, out, cstate, chunk, s0);
    }
}